// Round 11
// baseline (159.410 us; speedup 1.0000x reference)
//
#include <hip/hip_runtime.h>
#include <hip/hip_bf16.h>

#define N_NODES 50000
#define E_EDGES 800000
#define NHEAD 4
#define DHEAD 32
#define DOUT 128   // NHEAD*DHEAD == D_IN
#define NEG_SLOPE 0.01f
#define EPS_F 1e-16f
#define DMAX 256
#define ELP 264    // EL head pitch (words); 264%32==8 -> heads hit distinct banks
#define NB 196     // dst buckets of 256 nodes (dst>>8), 49999>>8 == 195
#define CAP 8192   // payload capacity per bucket (mean 4096, sigma 64)

typedef __attribute__((ext_vector_type(8))) short bf16x8;
typedef __attribute__((ext_vector_type(4))) float f32x4;

__device__ __forceinline__ float bf2f(unsigned short u) {
    return __uint_as_float((unsigned)u << 16);
}
__device__ __forceinline__ unsigned short f2bf(float f) {
    return __bfloat16_as_ushort(__float2bfloat16(f));   // RNE
}

// ---- edge index fetch, robust to int32 vs int64 storage ----
__device__ __forceinline__ void load_edge(const int* __restrict__ ei, int isI64,
                                          int e, int& src, int& dst) {
    if (isI64) { src = ei[2 * e]; dst = ei[2 * (E_EDGES + e)]; }
    else       { src = ei[e];     dst = ei[E_EDGES + e]; }
}

// ---- K0: weights -> MFMA-fragment-ordered bf16 (blocks 0..255) + detect ----
__global__ __launch_bounds__(128) void k_prep(const float* __restrict__ Wp,
                                              const float* __restrict__ Ws,
                                              const int* __restrict__ ei,
                                              unsigned short* __restrict__ Wt,
                                              int* __restrict__ flag) {
    int b = blockIdx.x;
    if (b < 256) {
        int c = b, k = threadIdx.x;   // col c of [Wp|Ws], row k
        float v = (c < DOUT) ? Wp[k * DOUT + c] : Ws[k * DOUT + (c - DOUT)];
        int nf = c >> 4, cl = c & 15;
        int ks = k >> 5, r = k & 31, lq = r >> 3, e = r & 7;
        Wt[(((nf * 4 + ks) << 6) + lq * 16 + cl) * 8 + e] = f2bf(v);
    } else {
        __shared__ int cnt;
        if (threadIdx.x == 0) cnt = 0;
        __syncthreads();
        int nz = 0;
        #pragma unroll
        for (int k2 = 0; k2 < 16; ++k2) {
            int pos = (threadIdx.x + k2 * 128) * 2 + 1;   // odd int32 slots
            if (ei[pos] != 0) nz = 1;
        }
        if (nz) atomicOr(&cnt, 1);
        __syncthreads();
        if (threadIdx.x == 0) *flag = (cnt == 0) ? 1 : 0;
    }
}

// ---- K1: MFMA GEMM [hb | out] = bf16(x) @ [Wp | Ws], fused attdot epilogue ----
// (unchanged from R9 — all global traffic coalesced, A via swizzled LDS)
#define HBP 136    // bf16 LDS h-tile pitch (68 words)
#define SKP 132    // f32 LDS skip-tile pitch
__global__ __launch_bounds__(256) void k_gemm(const float* __restrict__ x,
                                              const unsigned short* __restrict__ Wt,
                                              const float* __restrict__ att,
                                              unsigned short* __restrict__ hb,
                                              float* __restrict__ as_,
                                              float* __restrict__ ad_,
                                              float* __restrict__ out) {
    __shared__ float SK[64 * SKP];            // 33792 B; first acts as x-stage
    __shared__ unsigned short HB[64 * HBP];   // 17408 B
    char* XSc = (char*)SK;

    const int tid = threadIdx.x;
    const int rw  = tid >> 6;
    const int l   = tid & 63;
    const int l15 = l & 15;
    const int lq  = l >> 4;

    {
        int d = tid * 16;
        #pragma unroll
        for (int it = 0; it < 8; ++it, d += 4096) {
            int row = d >> 9, col = d & 511;
            int grow = blockIdx.x * 64 + row;
            if (grow > N_NODES - 1) grow = N_NODES - 1;
            float4 v = *(const float4*)((const char*)x + (size_t)grow * 512 + col);
            *(float4*)(XSc + (row << 9) + (col ^ ((row & 7) << 4))) = v;
        }
    }
    __syncthreads();

    const int rl = rw * 16 + l15;
    const int sw = (rl & 7) << 4;
    bf16x8 afr[4];
    #pragma unroll
    for (int ks = 0; ks < 4; ++ks) {
        int c0 = ks * 128 + lq * 32;
        float4 u0 = *(const float4*)(XSc + (rl << 9) + (c0 ^ sw));
        float4 u1 = *(const float4*)(XSc + (rl << 9) + ((c0 + 16) ^ sw));
        bf16x8 a;
        a[0] = (short)f2bf(u0.x); a[1] = (short)f2bf(u0.y);
        a[2] = (short)f2bf(u0.z); a[3] = (short)f2bf(u0.w);
        a[4] = (short)f2bf(u1.x); a[5] = (short)f2bf(u1.y);
        a[6] = (short)f2bf(u1.z); a[7] = (short)f2bf(u1.w);
        afr[ks] = a;
    }
    __syncthreads();   // x-stage dead; SK reusable for skip tile

    f32x4 acc[16];
    #pragma unroll
    for (int nf = 0; nf < 16; ++nf) acc[nf] = (f32x4)(0.0f);

    #pragma unroll
    for (int nf = 0; nf < 16; ++nf) {
        #pragma unroll
        for (int ks = 0; ks < 4; ++ks) {
            bf16x8 b = *(const bf16x8*)(Wt + ((((nf * 4 + ks) << 6) + l) << 3));
            acc[nf] = __builtin_amdgcn_mfma_f32_16x16x32_bf16(afr[ks], b, acc[nf], 0, 0, 0);
        }
    }

    #pragma unroll
    for (int nf = 0; nf < 8; ++nf) {
        #pragma unroll
        for (int q = 0; q < 4; ++q) {
            int r2 = rw * 16 + lq * 4 + q;
            HB[r2 * HBP + nf * 16 + l15] = f2bf(acc[nf][q]);
        }
    }
    #pragma unroll
    for (int nf = 8; nf < 16; ++nf) {
        #pragma unroll
        for (int q = 0; q < 4; ++q) {
            int r2 = rw * 16 + lq * 4 + q;
            SK[r2 * SKP + (nf - 8) * 16 + l15] = acc[nf][q];
        }
    }
    __syncthreads();

    {
        int rl2 = tid >> 2, hd = tid & 3;
        const unsigned* HBu = (const unsigned*)HB;
        const float* a1 = att + hd * 2 * DHEAD;
        const float* a2 = a1 + DHEAD;
        float s1 = 0.0f, s2 = 0.0f;
        #pragma unroll
        for (int j = 0; j < 16; ++j) {
            unsigned u = HBu[rl2 * (HBP / 2) + hd * 16 + j];
            float lo = bf2f((unsigned short)(u & 0xffff));
            float hi = bf2f((unsigned short)(u >> 16));
            s1 += lo * a1[2 * j] + hi * a1[2 * j + 1];
            s2 += lo * a2[2 * j] + hi * a2[2 * j + 1];
        }
        int rowg = blockIdx.x * 64 + rl2;     // as_/ad_ padded to 50048
        as_[(size_t)rowg * 4 + hd] = s1;
        ad_[(size_t)rowg * 4 + hd] = s2;
    }

    {
        const unsigned* HBu = (const unsigned*)HB;
        #pragma unroll
        for (int it = 0; it < 4; ++it) {
            int idx = it * 256 + tid;        // 0..1023
            int row = idx >> 4, g = idx & 15;
            int wb = row * (HBP / 2) + g * 4;
            uint4 v;
            v.x = HBu[wb]; v.y = HBu[wb + 1]; v.z = HBu[wb + 2]; v.w = HBu[wb + 3];
            *(uint4*)(hb + ((size_t)(blockIdx.x * 64 + row)) * DOUT + g * 8) = v;
        }
    }
    {
        #pragma unroll
        for (int it = 0; it < 8; ++it) {
            int idx = it * 256 + tid;        // 0..2047
            int row = idx >> 5, c4 = idx & 31;
            int rowg = blockIdx.x * 64 + row;
            if (rowg < N_NODES) {
                float4 v = *(const float4*)&SK[row * SKP + c4 * 4];
                *(float4*)(out + (size_t)rowg * DOUT + c4 * 4) = v;
            }
        }
    }
}

// ---- K2a: bucket partition. 256 blocks x 3125 edges. Payload (dl<<16)|src. ----
__global__ __launch_bounds__(256) void k_part(const int* __restrict__ ei,
                                              const int* __restrict__ flag,
                                              int* __restrict__ bucketCnt,
                                              unsigned* __restrict__ payload) {
    __shared__ int hist[NB];
    __shared__ int curs[NB];
    const int t = threadIdx.x;
    const int base = blockIdx.x * 3125;
    const int isI64 = *flag;

    for (int i = t; i < NB; i += 256) hist[i] = 0;
    __syncthreads();
    for (int i = t; i < 3125; i += 256) {
        int src, dst;
        load_edge(ei, isI64, base + i, src, dst);
        if ((unsigned)dst < N_NODES) atomicAdd(&hist[dst >> 8], 1);
    }
    __syncthreads();
    for (int i = t; i < NB; i += 256)
        curs[i] = atomicAdd(&bucketCnt[i], hist[i]);
    __syncthreads();
    for (int i = t; i < 3125; i += 256) {
        int src, dst;
        load_edge(ei, isI64, base + i, src, dst);
        if ((unsigned)src >= N_NODES || (unsigned)dst >= N_NODES) continue;
        int b = dst >> 8;
        int pos = atomicAdd(&curs[b], 1);
        if (pos < CAP)
            payload[((size_t)b << 13) + pos] = ((unsigned)(dst & 255) << 16) | (unsigned)src;
    }
}

// ---- K2b: per-bucket CSR build: deg/ofs (bucket-based) + srcs scatter ----
__global__ __launch_bounds__(256) void k_csr(const int* __restrict__ bucketCnt,
                                             const unsigned* __restrict__ payload,
                                             int* __restrict__ deg,
                                             int* __restrict__ ofs,
                                             int* __restrict__ srcs) {
    __shared__ int h[256];
    __shared__ int cur[256];
    __shared__ int sc[256];
    const int b = blockIdx.x;
    const int t = threadIdx.x;
    int cnt = bucketCnt[b];
    if (cnt > CAP) cnt = CAP;
    const unsigned* __restrict__ pl = payload + ((size_t)b << 13);

    h[t] = 0;
    __syncthreads();
    for (int i = t; i < cnt; i += 256) atomicAdd(&h[pl[i] >> 16], 1);
    __syncthreads();
    int v = h[t];
    sc[t] = v;
    __syncthreads();
    #pragma unroll
    for (int off = 1; off < 256; off <<= 1) {
        int u = (t >= off) ? sc[t - off] : 0;
        __syncthreads();
        sc[t] += u;
        __syncthreads();
    }
    int ex = sc[t] - v;              // exclusive local prefix
    cur[t] = ex;
    int n = (b << 8) + t;
    if (n < N_NODES) { deg[n] = v; ofs[n] = (b << 13) + ex; }
    __syncthreads();
    for (int i = t; i < cnt; i += 256) {
        unsigned p = pl[i];
        int pos = atomicAdd(&cur[p >> 16], 1);
        srcs[((size_t)b << 13) + pos] = (int)(p & 0xFFFFu);
    }
}

// ---- K3: per-node gather v5: R9 structure + 2 WAVES per node on phase D ----
// 256 threads = 4 waves = 2 nodes x 2 waves. Wave wh of a node processes
// edges i ≡ wh (mod 2): halves the serial dependent-load chain, doubles
// in-flight gathers. Wave 1 deposits partials in LDS; wave 0 combines+stores
// (it holds den in registers from phase C).
__global__ __launch_bounds__(256) void k_gat(const int* __restrict__ ofs,
                                             const int* __restrict__ deg,
                                             const int* __restrict__ srcs,
                                             const float* __restrict__ as_,
                                             const float* __restrict__ ad_,
                                             const unsigned short* __restrict__ hb,
                                             float* __restrict__ out) {
    __shared__ float  EL[2][NHEAD * ELP];   // 2 x 4.2 KB
    __shared__ int    SRC[2][DMAX];         // 2 x 1 KB
    __shared__ float2 PART[2][64];          // 2 x 512 B

    const int tid  = threadIdx.x;
    const int sub  = tid >> 7;             // node slot in block
    const int t128 = tid & 127;            // thread within node group
    const int wh   = (tid >> 6) & 1;       // which wave of the node
    const int k    = tid & 63;             // lane: col pair {2k,2k+1}
    const int hd   = k >> 4;
    const int l16  = k & 15;
    const int n = blockIdx.x * 2 + sub;    // 25000*2 == 50000 exactly
    const int o = ofs[n];
    const int d = deg[n];
    const unsigned* __restrict__ hbu = (const unsigned*)hb;
    float* ELn = EL[sub];
    int*   SRCn = SRC[sub];

    int fast = __syncthreads_and(d <= DMAX);   // block-uniform branch

    if (fast) {
        // phase AB (128 threads/node): srcs + leaky-relu logits, all 4 heads
        const float4 adv4 = *(const float4*)(ad_ + (size_t)n * 4);
        for (int e = t128; e < d; e += 128) {
            int s = srcs[o + e];
            SRCn[e] = s;
            float4 a4 = *(const float4*)(as_ + (size_t)s * 4);
            float e0 = a4.x + adv4.x, e1 = a4.y + adv4.y;
            float e2 = a4.z + adv4.z, e3 = a4.w + adv4.w;
            ELn[0 * ELP + e] = (e0 > 0.0f) ? e0 : NEG_SLOPE * e0;
            ELn[1 * ELP + e] = (e1 > 0.0f) ? e1 : NEG_SLOPE * e1;
            ELn[2 * ELP + e] = (e2 > 0.0f) ? e2 : NEG_SLOPE * e2;
            ELn[3 * ELP + e] = (e3 > 0.0f) ? e3 : NEG_SLOPE * e3;
        }
        __syncthreads();
        // phase C (wave 0 of the node only): per-head max, exp in place, denom
        float den = 0.0f;
        if (wh == 0) {
            float m = -3.4e38f;
            for (int i = l16; i < d; i += 16) m = fmaxf(m, ELn[hd * ELP + i]);
            #pragma unroll
            for (int off = 8; off; off >>= 1) m = fmaxf(m, __shfl_xor(m, off));
            for (int i = l16; i < d; i += 16) {
                float p = __expf(ELn[hd * ELP + i] - m);
                ELn[hd * ELP + i] = p;
                den += p;
            }
            #pragma unroll
            for (int off = 8; off; off >>= 1) den += __shfl_xor(den, off);
        }
        __syncthreads();
        // phase D: edge-parity split across the node's 2 waves
        float num0 = 0.0f, num1 = 0.0f;
        for (int i = wh; i < d; i += 2) {
            float p = ELn[hd * ELP + i];
            int s = SRCn[i];
            unsigned u = hbu[(size_t)s * (DOUT / 2) + k];
            num0 = fmaf(p, bf2f((unsigned short)(u & 0xffff)), num0);
            num1 = fmaf(p, bf2f((unsigned short)(u >> 16)), num1);
        }
        if (wh == 1) PART[sub][k] = make_float2(num0, num1);
        __syncthreads();
        if (wh == 0) {
            float2 pr = PART[sub][k];
            num0 += pr.x; num1 += pr.y;
            float inv = 1.0f / (den + EPS_F);
            float2* op = (float2*)(out + (size_t)n * DOUT + 2 * k);
            float2 sk = *op;
            *op = make_float2(num0 * inv + sk.x, num1 * inv + sk.y);
        }
    } else {
        // fallback (degree > DMAX): wave 0 of the node runs R9's scalar path
        if (wh == 0) {
            const float adv = ad_[(size_t)n * 4 + hd];
            float m = -3.4e38f;
            for (int i = 0; i < d; ++i) {
                float el = as_[(size_t)srcs[o + i] * 4 + hd] + adv;
                el = (el > 0.0f) ? el : NEG_SLOPE * el;
                m = fmaxf(m, el);
            }
            float den = 0.0f, num0 = 0.0f, num1 = 0.0f;
            for (int i = 0; i < d; ++i) {
                int s = srcs[o + i];
                float el = as_[(size_t)s * 4 + hd] + adv;
                el = (el > 0.0f) ? el : NEG_SLOPE * el;
                float p = __expf(el - m);
                den += p;
                unsigned u = hbu[(size_t)s * (DOUT / 2) + k];
                num0 = fmaf(p, bf2f((unsigned short)(u & 0xffff)), num0);
                num1 = fmaf(p, bf2f((unsigned short)(u >> 16)), num1);
            }
            float inv = 1.0f / (den + EPS_F);
            float2* op = (float2*)(out + (size_t)n * DOUT + 2 * k);
            float2 sk = *op;
            *op = make_float2(num0 * inv + sk.x, num1 * inv + sk.y);
        }
    }
}

extern "C" void kernel_launch(void* const* d_in, const int* in_sizes, int n_in,
                              void* d_out, int out_size, void* d_ws, size_t ws_size,
                              hipStream_t stream) {
    const float* x   = (const float*)d_in[0];
    const float* Wp  = (const float*)d_in[1];
    const float* att = (const float*)d_in[2];
    const float* Ws  = (const float*)d_in[3];
    const int*   ei  = (const int*)d_in[4];
    float* out = (float*)d_out;

    char* ws = (char*)d_ws;
    unsigned short* hb        = (unsigned short*)(ws);              // 12,812,288 B (50048 rows)
    unsigned short* Wt        = (unsigned short*)(ws + 12812288);   // 65,536 B
    float*          as_       = (float*)(ws + 12877824);            // 800,768 B
    float*          ad_       = (float*)(ws + 13678592);            // 800,768 B
    int*            deg       = (int*)(ws + 14479360);              // 200,704 B
    int*            ofs       = (int*)(ws + 14680064);              // 200,704 B
    unsigned*       payload   = (unsigned*)(ws + 14880768);         // 6,422,528 B
    int*            srcs      = (int*)(ws + 21303296);              // 6,422,528 B
    int*            bucketCnt = (int*)(ws + 27725824);              // 1,024 B
    int*            flag      = (int*)(ws + 27726848);

    hipMemsetAsync(bucketCnt, 0, NB * 4, stream);

    k_prep<<<257, 128, 0, stream>>>(Wp, Ws, ei, Wt, flag);
    k_gemm<<<(N_NODES + 63) / 64, 256, 0, stream>>>(x, Wt, att, hb, as_, ad_, out);
    k_part<<<256, 256, 0, stream>>>(ei, flag, bucketCnt, payload);
    k_csr<<<NB, 256, 0, stream>>>(bucketCnt, payload, deg, ofs, srcs);
    k_gat<<<N_NODES / 2, 256, 0, stream>>>(ofs, deg, srcs, as_, ad_, hb, out);
}

// Round 12
// 118.182 us; speedup vs baseline: 1.3488x; 1.3488x over previous
//
#include <hip/hip_runtime.h>
#include <hip/hip_bf16.h>

#define N_NODES 50000
#define E_EDGES 800000
#define NHEAD 4
#define DHEAD 32
#define DOUT 128   // NHEAD*DHEAD == D_IN
#define NEG_SLOPE 0.01f
#define EPS_F 1e-16f
#define DMAX 256
#define ELP 264    // EL head pitch (words); 264%32==8 -> heads hit distinct banks
#define NB 196     // dst buckets of 256 nodes (dst>>8), 49999>>8 == 195
#define CAP 8192   // payload capacity per bucket (mean 4096, sigma 64)

typedef __attribute__((ext_vector_type(8))) short bf16x8;
typedef __attribute__((ext_vector_type(4))) float f32x4;

__device__ __forceinline__ float bf2f(unsigned short u) {
    return __uint_as_float((unsigned)u << 16);
}
__device__ __forceinline__ unsigned short f2bf(float f) {
    return __bfloat16_as_ushort(__float2bfloat16(f));   // RNE
}

// ---- edge index fetch, robust to int32 vs int64 storage ----
__device__ __forceinline__ void load_edge(const int* __restrict__ ei, int isI64,
                                          int e, int& src, int& dst) {
    if (isI64) { src = ei[2 * e]; dst = ei[2 * (E_EDGES + e)]; }
    else       { src = ei[e];     dst = ei[E_EDGES + e]; }
}

// ---- K0: weights -> MFMA-fragment-ordered bf16 (blocks 0..255) + detect ----
__global__ __launch_bounds__(128) void k_prep(const float* __restrict__ Wp,
                                              const float* __restrict__ Ws,
                                              const int* __restrict__ ei,
                                              unsigned short* __restrict__ Wt,
                                              int* __restrict__ flag) {
    int b = blockIdx.x;
    if (b < 256) {
        int c = b, k = threadIdx.x;   // col c of [Wp|Ws], row k
        float v = (c < DOUT) ? Wp[k * DOUT + c] : Ws[k * DOUT + (c - DOUT)];
        int nf = c >> 4, cl = c & 15;
        int ks = k >> 5, r = k & 31, lq = r >> 3, e = r & 7;
        Wt[(((nf * 4 + ks) << 6) + lq * 16 + cl) * 8 + e] = f2bf(v);
    } else {
        __shared__ int cnt;
        if (threadIdx.x == 0) cnt = 0;
        __syncthreads();
        int nz = 0;
        #pragma unroll
        for (int k2 = 0; k2 < 16; ++k2) {
            int pos = (threadIdx.x + k2 * 128) * 2 + 1;   // odd int32 slots
            if (ei[pos] != 0) nz = 1;
        }
        if (nz) atomicOr(&cnt, 1);
        __syncthreads();
        if (threadIdx.x == 0) *flag = (cnt == 0) ? 1 : 0;
    }
}

// ---- K1: MFMA GEMM [hb | out] = bf16(x) @ [Wp | Ws], fused attdot epilogue ----
// (unchanged from R9 — all global traffic coalesced, A via swizzled LDS)
#define HBP 136    // bf16 LDS h-tile pitch (68 words)
#define SKP 132    // f32 LDS skip-tile pitch
__global__ __launch_bounds__(256) void k_gemm(const float* __restrict__ x,
                                              const unsigned short* __restrict__ Wt,
                                              const float* __restrict__ att,
                                              unsigned short* __restrict__ hb,
                                              float* __restrict__ as_,
                                              float* __restrict__ ad_,
                                              float* __restrict__ out) {
    __shared__ float SK[64 * SKP];            // 33792 B; first acts as x-stage
    __shared__ unsigned short HB[64 * HBP];   // 17408 B
    char* XSc = (char*)SK;

    const int tid = threadIdx.x;
    const int rw  = tid >> 6;
    const int l   = tid & 63;
    const int l15 = l & 15;
    const int lq  = l >> 4;

    {
        int d = tid * 16;
        #pragma unroll
        for (int it = 0; it < 8; ++it, d += 4096) {
            int row = d >> 9, col = d & 511;
            int grow = blockIdx.x * 64 + row;
            if (grow > N_NODES - 1) grow = N_NODES - 1;
            float4 v = *(const float4*)((const char*)x + (size_t)grow * 512 + col);
            *(float4*)(XSc + (row << 9) + (col ^ ((row & 7) << 4))) = v;
        }
    }
    __syncthreads();

    const int rl = rw * 16 + l15;
    const int sw = (rl & 7) << 4;
    bf16x8 afr[4];
    #pragma unroll
    for (int ks = 0; ks < 4; ++ks) {
        int c0 = ks * 128 + lq * 32;
        float4 u0 = *(const float4*)(XSc + (rl << 9) + (c0 ^ sw));
        float4 u1 = *(const float4*)(XSc + (rl << 9) + ((c0 + 16) ^ sw));
        bf16x8 a;
        a[0] = (short)f2bf(u0.x); a[1] = (short)f2bf(u0.y);
        a[2] = (short)f2bf(u0.z); a[3] = (short)f2bf(u0.w);
        a[4] = (short)f2bf(u1.x); a[5] = (short)f2bf(u1.y);
        a[6] = (short)f2bf(u1.z); a[7] = (short)f2bf(u1.w);
        afr[ks] = a;
    }
    __syncthreads();   // x-stage dead; SK reusable for skip tile

    f32x4 acc[16];
    #pragma unroll
    for (int nf = 0; nf < 16; ++nf) acc[nf] = (f32x4)(0.0f);

    #pragma unroll
    for (int nf = 0; nf < 16; ++nf) {
        #pragma unroll
        for (int ks = 0; ks < 4; ++ks) {
            bf16x8 b = *(const bf16x8*)(Wt + ((((nf * 4 + ks) << 6) + l) << 3));
            acc[nf] = __builtin_amdgcn_mfma_f32_16x16x32_bf16(afr[ks], b, acc[nf], 0, 0, 0);
        }
    }

    #pragma unroll
    for (int nf = 0; nf < 8; ++nf) {
        #pragma unroll
        for (int q = 0; q < 4; ++q) {
            int r2 = rw * 16 + lq * 4 + q;
            HB[r2 * HBP + nf * 16 + l15] = f2bf(acc[nf][q]);
        }
    }
    #pragma unroll
    for (int nf = 8; nf < 16; ++nf) {
        #pragma unroll
        for (int q = 0; q < 4; ++q) {
            int r2 = rw * 16 + lq * 4 + q;
            SK[r2 * SKP + (nf - 8) * 16 + l15] = acc[nf][q];
        }
    }
    __syncthreads();

    {
        int rl2 = tid >> 2, hd = tid & 3;
        const unsigned* HBu = (const unsigned*)HB;
        const float* a1 = att + hd * 2 * DHEAD;
        const float* a2 = a1 + DHEAD;
        float s1 = 0.0f, s2 = 0.0f;
        #pragma unroll
        for (int j = 0; j < 16; ++j) {
            unsigned u = HBu[rl2 * (HBP / 2) + hd * 16 + j];
            float lo = bf2f((unsigned short)(u & 0xffff));
            float hi = bf2f((unsigned short)(u >> 16));
            s1 += lo * a1[2 * j] + hi * a1[2 * j + 1];
            s2 += lo * a2[2 * j] + hi * a2[2 * j + 1];
        }
        int rowg = blockIdx.x * 64 + rl2;     // as_/ad_ padded to 50048
        as_[(size_t)rowg * 4 + hd] = s1;
        ad_[(size_t)rowg * 4 + hd] = s2;
    }

    {
        const unsigned* HBu = (const unsigned*)HB;
        #pragma unroll
        for (int it = 0; it < 4; ++it) {
            int idx = it * 256 + tid;        // 0..1023
            int row = idx >> 4, g = idx & 15;
            int wb = row * (HBP / 2) + g * 4;
            uint4 v;
            v.x = HBu[wb]; v.y = HBu[wb + 1]; v.z = HBu[wb + 2]; v.w = HBu[wb + 3];
            *(uint4*)(hb + ((size_t)(blockIdx.x * 64 + row)) * DOUT + g * 8) = v;
        }
    }
    {
        #pragma unroll
        for (int it = 0; it < 8; ++it) {
            int idx = it * 256 + tid;        // 0..2047
            int row = idx >> 5, c4 = idx & 31;
            int rowg = blockIdx.x * 64 + row;
            if (rowg < N_NODES) {
                float4 v = *(const float4*)&SK[row * SKP + c4 * 4];
                *(float4*)(out + (size_t)rowg * DOUT + c4 * 4) = v;
            }
        }
    }
}

// ---- K2a: bucket partition. 256 blocks x 3125 edges. Payload (dl<<16)|src. ----
__global__ __launch_bounds__(256) void k_part(const int* __restrict__ ei,
                                              const int* __restrict__ flag,
                                              int* __restrict__ bucketCnt,
                                              unsigned* __restrict__ payload) {
    __shared__ int hist[NB];
    __shared__ int curs[NB];
    const int t = threadIdx.x;
    const int base = blockIdx.x * 3125;
    const int isI64 = *flag;

    for (int i = t; i < NB; i += 256) hist[i] = 0;
    __syncthreads();
    for (int i = t; i < 3125; i += 256) {
        int src, dst;
        load_edge(ei, isI64, base + i, src, dst);
        if ((unsigned)dst < N_NODES) atomicAdd(&hist[dst >> 8], 1);
    }
    __syncthreads();
    for (int i = t; i < NB; i += 256)
        curs[i] = atomicAdd(&bucketCnt[i], hist[i]);
    __syncthreads();
    for (int i = t; i < 3125; i += 256) {
        int src, dst;
        load_edge(ei, isI64, base + i, src, dst);
        if ((unsigned)src >= N_NODES || (unsigned)dst >= N_NODES) continue;
        int b = dst >> 8;
        int pos = atomicAdd(&curs[b], 1);
        if (pos < CAP)
            payload[((size_t)b << 13) + pos] = ((unsigned)(dst & 255) << 16) | (unsigned)src;
    }
}

// ---- K2b: per-bucket CSR build: deg/ofs (bucket-based) + srcs scatter ----
__global__ __launch_bounds__(256) void k_csr(const int* __restrict__ bucketCnt,
                                             const unsigned* __restrict__ payload,
                                             int* __restrict__ deg,
                                             int* __restrict__ ofs,
                                             int* __restrict__ srcs) {
    __shared__ int h[256];
    __shared__ int cur[256];
    __shared__ int sc[256];
    const int b = blockIdx.x;
    const int t = threadIdx.x;
    int cnt = bucketCnt[b];
    if (cnt > CAP) cnt = CAP;
    const unsigned* __restrict__ pl = payload + ((size_t)b << 13);

    h[t] = 0;
    __syncthreads();
    for (int i = t; i < cnt; i += 256) atomicAdd(&h[pl[i] >> 16], 1);
    __syncthreads();
    int v = h[t];
    sc[t] = v;
    __syncthreads();
    #pragma unroll
    for (int off = 1; off < 256; off <<= 1) {
        int u = (t >= off) ? sc[t - off] : 0;
        __syncthreads();
        sc[t] += u;
        __syncthreads();
    }
    int ex = sc[t] - v;              // exclusive local prefix
    cur[t] = ex;
    int n = (b << 8) + t;
    if (n < N_NODES) { deg[n] = v; ofs[n] = (b << 13) + ex; }
    __syncthreads();
    for (int i = t; i < cnt; i += 256) {
        unsigned p = pl[i];
        int pos = atomicAdd(&cur[p >> 16], 1);
        srcs[((size_t)b << 13) + pos] = (int)(p & 0xFFFFu);
    }
}

// ---- K3: per-node gather v6: exact R9 structure, phase D unrolled x4 with ----
// ---- batched independent gathers (4 loads in flight before any FMA).     ----
__global__ __launch_bounds__(128) void k_gat(const int* __restrict__ ofs,
                                             const int* __restrict__ deg,
                                             const int* __restrict__ srcs,
                                             const float* __restrict__ as_,
                                             const float* __restrict__ ad_,
                                             const unsigned short* __restrict__ hb,
                                             float* __restrict__ out) {
    __shared__ float EL[2][NHEAD * ELP];   // 2 x 4.2 KB
    __shared__ int   SRC[2][DMAX];         // 2 x 1 KB

    const int sub = threadIdx.x >> 6;      // node slot in block
    const int k   = threadIdx.x & 63;
    const int hd  = k >> 4;
    const int l16 = k & 15;
    const int n = blockIdx.x * 2 + sub;    // 25000*2 == 50000 exactly
    const int o = ofs[n];
    const int d = deg[n];
    const unsigned* __restrict__ hbu = (const unsigned*)hb;
    float* ELn = EL[sub];
    int*   SRCn = SRC[sub];

    int fast = __syncthreads_and(d <= DMAX);   // block-uniform branch

    if (fast) {
        // phase AB: stage srcs + leaky-relu logits for all 4 heads
        const float4 adv4 = *(const float4*)(ad_ + (size_t)n * 4);
        for (int e = k; e < d; e += 64) {
            int s = srcs[o + e];
            SRCn[e] = s;
            float4 a4 = *(const float4*)(as_ + (size_t)s * 4);
            float e0 = a4.x + adv4.x, e1 = a4.y + adv4.y;
            float e2 = a4.z + adv4.z, e3 = a4.w + adv4.w;
            ELn[0 * ELP + e] = (e0 > 0.0f) ? e0 : NEG_SLOPE * e0;
            ELn[1 * ELP + e] = (e1 > 0.0f) ? e1 : NEG_SLOPE * e1;
            ELn[2 * ELP + e] = (e2 > 0.0f) ? e2 : NEG_SLOPE * e2;
            ELn[3 * ELP + e] = (e3 > 0.0f) ? e3 : NEG_SLOPE * e3;
        }
        __syncthreads();
        // phase C: per-head max (16-lane groups), exp in place, denom
        float m = -3.4e38f;
        for (int i = l16; i < d; i += 16) m = fmaxf(m, ELn[hd * ELP + i]);
        #pragma unroll
        for (int off = 8; off; off >>= 1) m = fmaxf(m, __shfl_xor(m, off));
        float den = 0.0f;
        for (int i = l16; i < d; i += 16) {
            float p = __expf(ELn[hd * ELP + i] - m);
            ELn[hd * ELP + i] = p;
            den += p;
        }
        #pragma unroll
        for (int off = 8; off; off >>= 1) den += __shfl_xor(den, off);
        __syncthreads();
        // phase D: weighted gather, unrolled x4 with loads batched ahead of FMAs
        float num0 = 0.0f, num1 = 0.0f;
        int i = 0;
        for (; i + 4 <= d; i += 4) {
            int s0 = SRCn[i], s1 = SRCn[i + 1], s2 = SRCn[i + 2], s3 = SRCn[i + 3];
            unsigned u0 = hbu[(size_t)s0 * (DOUT / 2) + k];
            unsigned u1 = hbu[(size_t)s1 * (DOUT / 2) + k];
            unsigned u2 = hbu[(size_t)s2 * (DOUT / 2) + k];
            unsigned u3 = hbu[(size_t)s3 * (DOUT / 2) + k];
            float p0 = ELn[hd * ELP + i];
            float p1 = ELn[hd * ELP + i + 1];
            float p2 = ELn[hd * ELP + i + 2];
            float p3 = ELn[hd * ELP + i + 3];
            num0 = fmaf(p0, bf2f((unsigned short)(u0 & 0xffff)), num0);
            num1 = fmaf(p0, bf2f((unsigned short)(u0 >> 16)), num1);
            num0 = fmaf(p1, bf2f((unsigned short)(u1 & 0xffff)), num0);
            num1 = fmaf(p1, bf2f((unsigned short)(u1 >> 16)), num1);
            num0 = fmaf(p2, bf2f((unsigned short)(u2 & 0xffff)), num0);
            num1 = fmaf(p2, bf2f((unsigned short)(u2 >> 16)), num1);
            num0 = fmaf(p3, bf2f((unsigned short)(u3 & 0xffff)), num0);
            num1 = fmaf(p3, bf2f((unsigned short)(u3 >> 16)), num1);
        }
        for (; i < d; ++i) {
            float p = ELn[hd * ELP + i];
            int s = SRCn[i];
            unsigned u = hbu[(size_t)s * (DOUT / 2) + k];
            num0 = fmaf(p, bf2f((unsigned short)(u & 0xffff)), num0);
            num1 = fmaf(p, bf2f((unsigned short)(u >> 16)), num1);
        }
        float inv = 1.0f / (den + EPS_F);
        float2* op = (float2*)(out + (size_t)n * DOUT + 2 * k);
        float2 sk = *op;
        *op = make_float2(num0 * inv + sk.x, num1 * inv + sk.y);
    } else {
        // fallback (degree > DMAX): scalar two-pass, 2 cols per lane
        const float adv = ad_[(size_t)n * 4 + hd];
        float m = -3.4e38f;
        for (int i = 0; i < d; ++i) {
            float el = as_[(size_t)srcs[o + i] * 4 + hd] + adv;
            el = (el > 0.0f) ? el : NEG_SLOPE * el;
            m = fmaxf(m, el);
        }
        float den = 0.0f, num0 = 0.0f, num1 = 0.0f;
        for (int i = 0; i < d; ++i) {
            int s = srcs[o + i];
            float el = as_[(size_t)s * 4 + hd] + adv;
            el = (el > 0.0f) ? el : NEG_SLOPE * el;
            float p = __expf(el - m);
            den += p;
            unsigned u = hbu[(size_t)s * (DOUT / 2) + k];
            num0 = fmaf(p, bf2f((unsigned short)(u & 0xffff)), num0);
            num1 = fmaf(p, bf2f((unsigned short)(u >> 16)), num1);
        }
        float inv = 1.0f / (den + EPS_F);
        float2* op = (float2*)(out + (size_t)n * DOUT + 2 * k);
        float2 sk = *op;
        *op = make_float2(num0 * inv + sk.x, num1 * inv + sk.y);
    }
}

extern "C" void kernel_launch(void* const* d_in, const int* in_sizes, int n_in,
                              void* d_out, int out_size, void* d_ws, size_t ws_size,
                              hipStream_t stream) {
    const float* x   = (const float*)d_in[0];
    const float* Wp  = (const float*)d_in[1];
    const float* att = (const float*)d_in[2];
    const float* Ws  = (const float*)d_in[3];
    const int*   ei  = (const int*)d_in[4];
    float* out = (float*)d_out;

    char* ws = (char*)d_ws;
    unsigned short* hb        = (unsigned short*)(ws);              // 12,812,288 B (50048 rows)
    unsigned short* Wt        = (unsigned short*)(ws + 12812288);   // 65,536 B
    float*          as_       = (float*)(ws + 12877824);            // 800,768 B
    float*          ad_       = (float*)(ws + 13678592);            // 800,768 B
    int*            deg       = (int*)(ws + 14479360);              // 200,704 B
    int*            ofs       = (int*)(ws + 14680064);              // 200,704 B
    unsigned*       payload   = (unsigned*)(ws + 14880768);         // 6,422,528 B
    int*            srcs      = (int*)(ws + 21303296);              // 6,422,528 B
    int*            bucketCnt = (int*)(ws + 27725824);              // 1,024 B
    int*            flag      = (int*)(ws + 27726848);

    hipMemsetAsync(bucketCnt, 0, NB * 4, stream);

    k_prep<<<257, 128, 0, stream>>>(Wp, Ws, ei, Wt, flag);
    k_gemm<<<(N_NODES + 63) / 64, 256, 0, stream>>>(x, Wt, att, hb, as_, ad_, out);
    k_part<<<256, 256, 0, stream>>>(ei, flag, bucketCnt, payload);
    k_csr<<<NB, 256, 0, stream>>>(bucketCnt, payload, deg, ofs, srcs);
    k_gat<<<N_NODES / 2, 128, 0, stream>>>(ofs, deg, srcs, as_, ad_, hb, out);
}

// Round 13
// 111.410 us; speedup vs baseline: 1.4308x; 1.0608x over previous
//
#include <hip/hip_runtime.h>
#include <hip/hip_bf16.h>

#define N_NODES 50000
#define E_EDGES 800000
#define NHEAD 4
#define DHEAD 32
#define DOUT 128   // NHEAD*DHEAD == D_IN
#define NEG_SLOPE 0.01f
#define EPS_F 1e-16f
#define DMAX 256
#define ELP 264    // EL head pitch (words); 264%32==8 -> heads hit distinct banks
#define NB 196     // dst buckets of 256 nodes (dst>>8), 49999>>8 == 195
#define CAP 8192   // payload capacity per bucket (mean 4096, sigma 64)
#define XSP 136    // bf16 x-stage pitch (272 B/row): rows spread 16B-granules over banks

typedef __attribute__((ext_vector_type(8))) short bf16x8;
typedef __attribute__((ext_vector_type(4))) float f32x4;

__device__ __forceinline__ float bf2f(unsigned short u) {
    return __uint_as_float((unsigned)u << 16);
}
__device__ __forceinline__ unsigned short f2bf(float f) {
    return __bfloat16_as_ushort(__float2bfloat16(f));   // RNE
}

// ---- edge index fetch, robust to int32 vs int64 storage ----
__device__ __forceinline__ void load_edge(const int* __restrict__ ei, int isI64,
                                          int e, int& src, int& dst) {
    if (isI64) { src = ei[2 * e]; dst = ei[2 * (E_EDGES + e)]; }
    else       { src = ei[e];     dst = ei[E_EDGES + e]; }
}

// ---- K0: weights -> MFMA-fragment-ordered bf16 (blocks 0..255) + detect ----
// Fragment order works as BOTH B-operand (col=lane&15) and A-operand
// (row=lane&15) since the lane->element maps coincide.
__global__ __launch_bounds__(128) void k_prep(const float* __restrict__ Wp,
                                              const float* __restrict__ Ws,
                                              const int* __restrict__ ei,
                                              unsigned short* __restrict__ Wt,
                                              int* __restrict__ flag) {
    int b = blockIdx.x;
    if (b < 256) {
        int c = b, k = threadIdx.x;   // col c of [Wp|Ws], row k
        float v = (c < DOUT) ? Wp[k * DOUT + c] : Ws[k * DOUT + (c - DOUT)];
        int nf = c >> 4, cl = c & 15;
        int ks = k >> 5, r = k & 31, lq = r >> 3, e = r & 7;
        Wt[(((nf * 4 + ks) << 6) + lq * 16 + cl) * 8 + e] = f2bf(v);
    } else {
        __shared__ int cnt;
        if (threadIdx.x == 0) cnt = 0;
        __syncthreads();
        int nz = 0;
        #pragma unroll
        for (int k2 = 0; k2 < 16; ++k2) {
            int pos = (threadIdx.x + k2 * 128) * 2 + 1;   // odd int32 slots
            if (ei[pos] != 0) nz = 1;
        }
        if (nz) atomicOr(&cnt, 1);
        __syncthreads();
        if (threadIdx.x == 0) *flag = (cnt == 0) ? 1 : 0;
    }
}

// ---- K1: FUSED  [blocks 0..255: bucket partition] [blocks 256..1037: GEMM] ----
// GEMM computes D^T = mfma(A=W-frag, B=x-frag): lane holds 4 CONSECUTIVE output
// cols of node row (lane&15) -> register float4 epilogue, no result LDS tiles,
// one barrier. attdot folded in-register via shfl_xor over the 4 lq lanes.
__global__ __launch_bounds__(256) void k_gemm_part(const float* __restrict__ x,
                                                   const unsigned short* __restrict__ Wt,
                                                   const float* __restrict__ att,
                                                   const int* __restrict__ ei,
                                                   const int* __restrict__ flag,
                                                   int* __restrict__ bucketCnt,
                                                   unsigned* __restrict__ payload,
                                                   unsigned short* __restrict__ hb,
                                                   float* __restrict__ as_,
                                                   float* __restrict__ ad_,
                                                   float* __restrict__ out) {
    __shared__ __align__(16) char BUF[64 * XSP * 2];   // 17408 B, unioned
    const int tid = threadIdx.x;

    if (blockIdx.x < 256) {
        // ================= bucket partition (was k_part) =================
        int* hist = (int*)BUF;
        int* curs = hist + NB;
        const int base = blockIdx.x * 3125;
        const int isI64 = *flag;

        for (int i = tid; i < NB; i += 256) hist[i] = 0;
        __syncthreads();
        for (int i = tid; i < 3125; i += 256) {
            int src, dst;
            load_edge(ei, isI64, base + i, src, dst);
            if ((unsigned)dst < N_NODES) atomicAdd(&hist[dst >> 8], 1);
        }
        __syncthreads();
        for (int i = tid; i < NB; i += 256)
            curs[i] = atomicAdd(&bucketCnt[i], hist[i]);
        __syncthreads();
        for (int i = tid; i < 3125; i += 256) {
            int src, dst;
            load_edge(ei, isI64, base + i, src, dst);
            if ((unsigned)src >= N_NODES || (unsigned)dst >= N_NODES) continue;
            int b = dst >> 8;
            int pos = atomicAdd(&curs[b], 1);
            if (pos < CAP)
                payload[((size_t)b << 13) + pos] = ((unsigned)(dst & 255) << 16) | (unsigned)src;
        }
        return;
    }

    // ============================ GEMM ============================
    unsigned short* XSB = (unsigned short*)BUF;   // [64][XSP] bf16
    const int gb  = blockIdx.x - 256;             // 0..781
    const int rw  = tid >> 6;
    const int l   = tid & 63;
    const int l15 = l & 15;
    const int lq  = l >> 4;
    const int rowbase = gb * 64 + rw * 16;

    // stage x[64][128] -> bf16 LDS (coalesced float4 reads, 8B writes)
    {
        #pragma unroll
        for (int it = 0; it < 8; ++it) {
            int e = it * 1024 + tid * 4;          // element index
            int row = e >> 7, col = e & 127;
            int grow = gb * 64 + row;
            if (grow > N_NODES - 1) grow = N_NODES - 1;
            float4 v = *(const float4*)(x + (size_t)grow * DOUT + col);
            ushort4 pk = make_ushort4(f2bf(v.x), f2bf(v.y), f2bf(v.z), f2bf(v.w));
            *(ushort4*)(XSB + row * XSP + col) = pk;
        }
    }
    __syncthreads();

    // A... (actually B-operand) fragments of x: one ds_read_b128 per ks
    bf16x8 xfr[4];
    const char* xrow = (const char*)XSB + (rw * 16 + l15) * (XSP * 2);
    #pragma unroll
    for (int ks = 0; ks < 4; ++ks)
        xfr[ks] = *(const bf16x8*)(xrow + ks * 64 + lq * 16);

    f32x4 acc[16];
    #pragma unroll
    for (int nf = 0; nf < 16; ++nf) acc[nf] = (f32x4)(0.0f);

    // D^T: A = W fragment, B = x fragment
    #pragma unroll
    for (int nf = 0; nf < 16; ++nf) {
        #pragma unroll
        for (int ks = 0; ks < 4; ++ks) {
            bf16x8 w = *(const bf16x8*)(Wt + ((((nf * 4 + ks) << 6) + l) << 3));
            acc[nf] = __builtin_amdgcn_mfma_f32_16x16x32_bf16(w, xfr[ks], acc[nf], 0, 0, 0);
        }
    }

    const int r = rowbase + l15;                  // this lane's node row
    // h half: hb 8B stores + in-register attdot partials
    float ps1[4] = {0.f, 0.f, 0.f, 0.f}, ps2[4] = {0.f, 0.f, 0.f, 0.f};
    #pragma unroll
    for (int nf = 0; nf < 8; ++nf) {
        int hd = nf >> 1;
        int jb = (nf & 1) * 16 + lq * 4;          // col within head
        float4 w1 = *(const float4*)(att + hd * 2 * DHEAD + jb);
        float4 w2 = *(const float4*)(att + hd * 2 * DHEAD + DHEAD + jb);
        f32x4 v = acc[nf];
        ps1[hd] += v[0] * w1.x + v[1] * w1.y + v[2] * w1.z + v[3] * w1.w;
        ps2[hd] += v[0] * w2.x + v[1] * w2.y + v[2] * w2.z + v[3] * w2.w;
        ushort4 pk = make_ushort4(f2bf(v[0]), f2bf(v[1]), f2bf(v[2]), f2bf(v[3]));
        *(ushort4*)(hb + (size_t)r * DOUT + nf * 16 + lq * 4) = pk;   // hb padded
    }
    // reduce attdot over the 4 lq lanes (xor 16, 32)
    #pragma unroll
    for (int hd = 0; hd < 4; ++hd) {
        ps1[hd] += __shfl_xor(ps1[hd], 16); ps1[hd] += __shfl_xor(ps1[hd], 32);
        ps2[hd] += __shfl_xor(ps2[hd], 16); ps2[hd] += __shfl_xor(ps2[hd], 32);
    }
    if (lq == 0) {
        #pragma unroll
        for (int hd = 0; hd < 4; ++hd) {          // as_/ad_ padded to 50048
            as_[(size_t)r * 4 + hd] = ps1[hd];
            ad_[(size_t)r * 4 + hd] = ps2[hd];
        }
    }
    // skip half: direct guarded float4 stores
    if (r < N_NODES) {
        #pragma unroll
        for (int nf = 8; nf < 16; ++nf) {
            f32x4 v = acc[nf];
            *(float4*)(out + (size_t)r * DOUT + (nf - 8) * 16 + lq * 4) =
                make_float4(v[0], v[1], v[2], v[3]);
        }
    }
}

// ---- K2b: per-bucket CSR build: deg/ofs (bucket-based) + srcs scatter ----
__global__ __launch_bounds__(256) void k_csr(const int* __restrict__ bucketCnt,
                                             const unsigned* __restrict__ payload,
                                             int* __restrict__ deg,
                                             int* __restrict__ ofs,
                                             int* __restrict__ srcs) {
    __shared__ int h[256];
    __shared__ int cur[256];
    __shared__ int sc[256];
    const int b = blockIdx.x;
    const int t = threadIdx.x;
    int cnt = bucketCnt[b];
    if (cnt > CAP) cnt = CAP;
    const unsigned* __restrict__ pl = payload + ((size_t)b << 13);

    h[t] = 0;
    __syncthreads();
    for (int i = t; i < cnt; i += 256) atomicAdd(&h[pl[i] >> 16], 1);
    __syncthreads();
    int v = h[t];
    sc[t] = v;
    __syncthreads();
    #pragma unroll
    for (int off = 1; off < 256; off <<= 1) {
        int u = (t >= off) ? sc[t - off] : 0;
        __syncthreads();
        sc[t] += u;
        __syncthreads();
    }
    int ex = sc[t] - v;              // exclusive local prefix
    cur[t] = ex;
    int n = (b << 8) + t;
    if (n < N_NODES) { deg[n] = v; ofs[n] = (b << 13) + ex; }
    __syncthreads();
    for (int i = t; i < cnt; i += 256) {
        unsigned p = pl[i];
        int pos = atomicAdd(&cur[p >> 16], 1);
        srcs[((size_t)b << 13) + pos] = (int)(p & 0xFFFFu);
    }
}

// ---- K3: per-node gather (R12 structure, pinned at its gather-throughput ----
// ---- floor ~47 us; R10/R11/R12 variants all failed to beat it)           ----
__global__ __launch_bounds__(128) void k_gat(const int* __restrict__ ofs,
                                             const int* __restrict__ deg,
                                             const int* __restrict__ srcs,
                                             const float* __restrict__ as_,
                                             const float* __restrict__ ad_,
                                             const unsigned short* __restrict__ hb,
                                             float* __restrict__ out) {
    __shared__ float EL[2][NHEAD * ELP];   // 2 x 4.2 KB
    __shared__ int   SRC[2][DMAX];         // 2 x 1 KB

    const int sub = threadIdx.x >> 6;      // node slot in block
    const int k   = threadIdx.x & 63;
    const int hd  = k >> 4;
    const int l16 = k & 15;
    const int n = blockIdx.x * 2 + sub;    // 25000*2 == 50000 exactly
    const int o = ofs[n];
    const int d = deg[n];
    const unsigned* __restrict__ hbu = (const unsigned*)hb;
    float* ELn = EL[sub];
    int*   SRCn = SRC[sub];

    int fast = __syncthreads_and(d <= DMAX);   // block-uniform branch

    if (fast) {
        const float4 adv4 = *(const float4*)(ad_ + (size_t)n * 4);
        for (int e = k; e < d; e += 64) {
            int s = srcs[o + e];
            SRCn[e] = s;
            float4 a4 = *(const float4*)(as_ + (size_t)s * 4);
            float e0 = a4.x + adv4.x, e1 = a4.y + adv4.y;
            float e2 = a4.z + adv4.z, e3 = a4.w + adv4.w;
            ELn[0 * ELP + e] = (e0 > 0.0f) ? e0 : NEG_SLOPE * e0;
            ELn[1 * ELP + e] = (e1 > 0.0f) ? e1 : NEG_SLOPE * e1;
            ELn[2 * ELP + e] = (e2 > 0.0f) ? e2 : NEG_SLOPE * e2;
            ELn[3 * ELP + e] = (e3 > 0.0f) ? e3 : NEG_SLOPE * e3;
        }
        __syncthreads();
        float m = -3.4e38f;
        for (int i = l16; i < d; i += 16) m = fmaxf(m, ELn[hd * ELP + i]);
        #pragma unroll
        for (int off = 8; off; off >>= 1) m = fmaxf(m, __shfl_xor(m, off));
        float den = 0.0f;
        for (int i = l16; i < d; i += 16) {
            float p = __expf(ELn[hd * ELP + i] - m);
            ELn[hd * ELP + i] = p;
            den += p;
        }
        #pragma unroll
        for (int off = 8; off; off >>= 1) den += __shfl_xor(den, off);
        __syncthreads();
        float num0 = 0.0f, num1 = 0.0f;
        int i = 0;
        for (; i + 4 <= d; i += 4) {
            int s0 = SRCn[i], s1 = SRCn[i + 1], s2 = SRCn[i + 2], s3 = SRCn[i + 3];
            unsigned u0 = hbu[(size_t)s0 * (DOUT / 2) + k];
            unsigned u1 = hbu[(size_t)s1 * (DOUT / 2) + k];
            unsigned u2 = hbu[(size_t)s2 * (DOUT / 2) + k];
            unsigned u3 = hbu[(size_t)s3 * (DOUT / 2) + k];
            float p0 = ELn[hd * ELP + i];
            float p1 = ELn[hd * ELP + i + 1];
            float p2 = ELn[hd * ELP + i + 2];
            float p3 = ELn[hd * ELP + i + 3];
            num0 = fmaf(p0, bf2f((unsigned short)(u0 & 0xffff)), num0);
            num1 = fmaf(p0, bf2f((unsigned short)(u0 >> 16)), num1);
            num0 = fmaf(p1, bf2f((unsigned short)(u1 & 0xffff)), num0);
            num1 = fmaf(p1, bf2f((unsigned short)(u1 >> 16)), num1);
            num0 = fmaf(p2, bf2f((unsigned short)(u2 & 0xffff)), num0);
            num1 = fmaf(p2, bf2f((unsigned short)(u2 >> 16)), num1);
            num0 = fmaf(p3, bf2f((unsigned short)(u3 & 0xffff)), num0);
            num1 = fmaf(p3, bf2f((unsigned short)(u3 >> 16)), num1);
        }
        for (; i < d; ++i) {
            float p = ELn[hd * ELP + i];
            int s = SRCn[i];
            unsigned u = hbu[(size_t)s * (DOUT / 2) + k];
            num0 = fmaf(p, bf2f((unsigned short)(u & 0xffff)), num0);
            num1 = fmaf(p, bf2f((unsigned short)(u >> 16)), num1);
        }
        float inv = 1.0f / (den + EPS_F);
        float2* op = (float2*)(out + (size_t)n * DOUT + 2 * k);
        float2 sk = *op;
        *op = make_float2(num0 * inv + sk.x, num1 * inv + sk.y);
    } else {
        const float adv = ad_[(size_t)n * 4 + hd];
        float m = -3.4e38f;
        for (int i = 0; i < d; ++i) {
            float el = as_[(size_t)srcs[o + i] * 4 + hd] + adv;
            el = (el > 0.0f) ? el : NEG_SLOPE * el;
            m = fmaxf(m, el);
        }
        float den = 0.0f, num0 = 0.0f, num1 = 0.0f;
        for (int i = 0; i < d; ++i) {
            int s = srcs[o + i];
            float el = as_[(size_t)s * 4 + hd] + adv;
            el = (el > 0.0f) ? el : NEG_SLOPE * el;
            float p = __expf(el - m);
            den += p;
            unsigned u = hbu[(size_t)s * (DOUT / 2) + k];
            num0 = fmaf(p, bf2f((unsigned short)(u & 0xffff)), num0);
            num1 = fmaf(p, bf2f((unsigned short)(u >> 16)), num1);
        }
        float inv = 1.0f / (den + EPS_F);
        float2* op = (float2*)(out + (size_t)n * DOUT + 2 * k);
        float2 sk = *op;
        *op = make_float2(num0 * inv + sk.x, num1 * inv + sk.y);
    }
}

extern "C" void kernel_launch(void* const* d_in, const int* in_sizes, int n_in,
                              void* d_out, int out_size, void* d_ws, size_t ws_size,
                              hipStream_t stream) {
    const float* x   = (const float*)d_in[0];
    const float* Wp  = (const float*)d_in[1];
    const float* att = (const float*)d_in[2];
    const float* Ws  = (const float*)d_in[3];
    const int*   ei  = (const int*)d_in[4];
    float* out = (float*)d_out;

    char* ws = (char*)d_ws;
    unsigned short* hb        = (unsigned short*)(ws);              // 12,812,288 B (50048 rows)
    unsigned short* Wt        = (unsigned short*)(ws + 12812288);   // 65,536 B
    float*          as_       = (float*)(ws + 12877824);            // 800,768 B
    float*          ad_       = (float*)(ws + 13678592);            // 800,768 B
    int*            deg       = (int*)(ws + 14479360);              // 200,704 B
    int*            ofs       = (int*)(ws + 14680064);              // 200,704 B
    unsigned*       payload   = (unsigned*)(ws + 14880768);         // 6,422,528 B
    int*            srcs      = (int*)(ws + 21303296);              // 6,422,528 B
    int*            bucketCnt = (int*)(ws + 27725824);              // 1,024 B
    int*            flag      = (int*)(ws + 27726848);

    hipMemsetAsync(bucketCnt, 0, NB * 4, stream);

    k_prep<<<257, 128, 0, stream>>>(Wp, Ws, ei, Wt, flag);
    k_gemm_part<<<256 + (N_NODES + 63) / 64, 256, 0, stream>>>(
        x, Wt, att, ei, flag, bucketCnt, payload, hb, as_, ad_, out);
    k_csr<<<NB, 256, 0, stream>>>(bucketCnt, payload, deg, ofs, srcs);
    k_gat<<<N_NODES / 2, 128, 0, stream>>>(ofs, deg, srcs, as_, ad_, hb, out);
}

// Round 14
// 98.993 us; speedup vs baseline: 1.6103x; 1.1254x over previous
//
#include <hip/hip_runtime.h>
#include <hip/hip_bf16.h>

#define N_NODES 50000
#define E_EDGES 800000
#define NHEAD 4
#define DHEAD 32
#define DOUT 128   // NHEAD*DHEAD == D_IN
#define NEG_SLOPE 0.01f
#define EPS_F 1e-16f
#define DMAX 256
#define ELP 264    // EL head pitch (words); 264%32==8 -> heads hit distinct banks
#define NB 196     // dst buckets of 256 nodes (dst>>8), 49999>>8 == 195
#define CAP 8192   // payload capacity per bucket (mean 4096, sigma 64)
#define XSP 136    // bf16 x-stage pitch (272 B/row)
#define NGB 782    // 782*64 == 50048 row-groups

typedef __attribute__((ext_vector_type(8))) short bf16x8;
typedef __attribute__((ext_vector_type(4))) float f32x4;

__device__ __forceinline__ float bf2f(unsigned short u) {
    return __uint_as_float((unsigned)u << 16);
}
__device__ __forceinline__ unsigned short f2bf(float f) {
    return __bfloat16_as_ushort(__float2bfloat16(f));   // RNE
}

// ---- edge index fetch, robust to int32 vs int64 storage ----
__device__ __forceinline__ void load_edge(const int* __restrict__ ei, int isI64,
                                          int e, int& src, int& dst) {
    if (isI64) { src = ei[2 * e]; dst = ei[2 * (E_EDGES + e)]; }
    else       { src = ei[e];     dst = ei[E_EDGES + e]; }
}

// ---- K0: weights -> MFMA-fragment-ordered bf16 (blocks 0..255); block 256:
// ---- int64-detect + bucketCnt zeroing (memset dispatch folded in).
__global__ __launch_bounds__(128) void k_prep(const float* __restrict__ Wp,
                                              const float* __restrict__ Ws,
                                              const int* __restrict__ ei,
                                              unsigned short* __restrict__ Wt,
                                              int* __restrict__ bucketCnt,
                                              int* __restrict__ flag) {
    int b = blockIdx.x;
    if (b < 256) {
        int c = b, k = threadIdx.x;   // col c of [Wp|Ws], row k
        float v = (c < DOUT) ? Wp[k * DOUT + c] : Ws[k * DOUT + (c - DOUT)];
        int nf = c >> 4, cl = c & 15;
        int ks = k >> 5, r = k & 31, lq = r >> 3, e = r & 7;
        Wt[(((nf * 4 + ks) << 6) + lq * 16 + cl) * 8 + e] = f2bf(v);
    } else {
        __shared__ int cnt;
        if (threadIdx.x == 0) cnt = 0;
        if (threadIdx.x < 128 && (int)threadIdx.x < NB) {
            bucketCnt[threadIdx.x] = 0;
            if (threadIdx.x + 128 < NB) bucketCnt[threadIdx.x + 128] = 0;
        }
        __syncthreads();
        int nz = 0;
        #pragma unroll
        for (int k2 = 0; k2 < 16; ++k2) {
            int pos = (threadIdx.x + k2 * 128) * 2 + 1;   // odd int32 slots
            if (ei[pos] != 0) nz = 1;
        }
        if (nz) atomicOr(&cnt, 1);
        __syncthreads();
        if (threadIdx.x == 0) *flag = (cnt == 0) ? 1 : 0;
    }
}

// ---- K1: FUSED [blocks 0..255: bucket partition][256..1819: split GEMM] ----
// GEMM pair (gb, half): same 64-row x-stage; half 0 -> nf 0-7 (hb + attdot),
// half 1 -> nf 8-15 (skip->out). Per wave: 32 MFMA, 32 KB Wt slice (L1-fits),
// acc = 32 AGPR. D^T = mfma(A=W-frag, B=x-frag); lane holds 4 consecutive
// output cols of node row (lane&15).
__global__ __launch_bounds__(256) void k_gemm_part(const float* __restrict__ x,
                                                   const unsigned short* __restrict__ Wt,
                                                   const float* __restrict__ att,
                                                   const int* __restrict__ ei,
                                                   const int* __restrict__ flag,
                                                   int* __restrict__ bucketCnt,
                                                   unsigned* __restrict__ payload,
                                                   unsigned short* __restrict__ hb,
                                                   float* __restrict__ as_,
                                                   float* __restrict__ ad_,
                                                   float* __restrict__ out) {
    __shared__ __align__(16) char BUF[64 * XSP * 2];   // 17408 B, unioned
    const int tid = threadIdx.x;

    if (blockIdx.x < 256) {
        // ================= bucket partition =================
        int* hist = (int*)BUF;
        int* curs = hist + NB;
        const int base = blockIdx.x * 3125;
        const int isI64 = *flag;

        for (int i = tid; i < NB; i += 256) hist[i] = 0;
        __syncthreads();
        for (int i = tid; i < 3125; i += 256) {
            int src, dst;
            load_edge(ei, isI64, base + i, src, dst);
            if ((unsigned)dst < N_NODES) atomicAdd(&hist[dst >> 8], 1);
        }
        __syncthreads();
        for (int i = tid; i < NB; i += 256)
            curs[i] = atomicAdd(&bucketCnt[i], hist[i]);
        __syncthreads();
        for (int i = tid; i < 3125; i += 256) {
            int src, dst;
            load_edge(ei, isI64, base + i, src, dst);
            if ((unsigned)src >= N_NODES || (unsigned)dst >= N_NODES) continue;
            int b = dst >> 8;
            int pos = atomicAdd(&curs[b], 1);
            if (pos < CAP)
                payload[((size_t)b << 13) + pos] = ((unsigned)(dst & 255) << 16) | (unsigned)src;
        }
        return;
    }

    // ============================ GEMM ============================
    unsigned short* XSB = (unsigned short*)BUF;   // [64][XSP] bf16
    const int gbp  = blockIdx.x - 256;            // 0..1563
    const int gb   = gbp >> 1;                    // row-group 0..781
    const int half = gbp & 1;                     // 0: h, 1: skip
    const int rw  = tid >> 6;
    const int l   = tid & 63;
    const int l15 = l & 15;
    const int lq  = l >> 4;
    const int rowbase = gb * 64 + rw * 16;

    // stage x[64][128] -> bf16 LDS (coalesced float4 reads, 8B writes)
    {
        #pragma unroll
        for (int it = 0; it < 8; ++it) {
            int e = it * 1024 + tid * 4;          // element index
            int row = e >> 7, col = e & 127;
            int grow = gb * 64 + row;
            if (grow > N_NODES - 1) grow = N_NODES - 1;
            float4 v = *(const float4*)(x + (size_t)grow * DOUT + col);
            ushort4 pk = make_ushort4(f2bf(v.x), f2bf(v.y), f2bf(v.z), f2bf(v.w));
            *(ushort4*)(XSB + row * XSP + col) = pk;
        }
    }
    __syncthreads();

    // x fragments (B-operand): one ds_read_b128 per ks
    bf16x8 xfr[4];
    const char* xrow = (const char*)XSB + (rw * 16 + l15) * (XSP * 2);
    #pragma unroll
    for (int ks = 0; ks < 4; ++ks)
        xfr[ks] = *(const bf16x8*)(xrow + ks * 64 + lq * 16);

    f32x4 acc[8];
    #pragma unroll
    for (int nf = 0; nf < 8; ++nf) acc[nf] = (f32x4)(0.0f);

    const int nfbase = half * 8;
    #pragma unroll
    for (int nf = 0; nf < 8; ++nf) {
        #pragma unroll
        for (int ks = 0; ks < 4; ++ks) {
            bf16x8 w = *(const bf16x8*)(Wt + (((((nfbase + nf) * 4 + ks) << 6) + l) << 3));
            acc[nf] = __builtin_amdgcn_mfma_f32_16x16x32_bf16(w, xfr[ks], acc[nf], 0, 0, 0);
        }
    }

    const int r = rowbase + l15;                  // this lane's node row
    if (half == 0) {
        // h half: hb 8B stores + in-register attdot partials
        float ps1[4] = {0.f, 0.f, 0.f, 0.f}, ps2[4] = {0.f, 0.f, 0.f, 0.f};
        #pragma unroll
        for (int nf = 0; nf < 8; ++nf) {
            int hd = nf >> 1;
            int jb = (nf & 1) * 16 + lq * 4;      // col within head
            float4 w1 = *(const float4*)(att + hd * 2 * DHEAD + jb);
            float4 w2 = *(const float4*)(att + hd * 2 * DHEAD + DHEAD + jb);
            f32x4 v = acc[nf];
            ps1[hd] += v[0] * w1.x + v[1] * w1.y + v[2] * w1.z + v[3] * w1.w;
            ps2[hd] += v[0] * w2.x + v[1] * w2.y + v[2] * w2.z + v[3] * w2.w;
            ushort4 pk = make_ushort4(f2bf(v[0]), f2bf(v[1]), f2bf(v[2]), f2bf(v[3]));
            *(ushort4*)(hb + (size_t)r * DOUT + nf * 16 + lq * 4) = pk;   // hb padded
        }
        #pragma unroll
        for (int hd = 0; hd < 4; ++hd) {
            ps1[hd] += __shfl_xor(ps1[hd], 16); ps1[hd] += __shfl_xor(ps1[hd], 32);
            ps2[hd] += __shfl_xor(ps2[hd], 16); ps2[hd] += __shfl_xor(ps2[hd], 32);
        }
        if (lq == 0) {
            #pragma unroll
            for (int hd = 0; hd < 4; ++hd) {      // as_/ad_ padded to 50048
                as_[(size_t)r * 4 + hd] = ps1[hd];
                ad_[(size_t)r * 4 + hd] = ps2[hd];
            }
        }
    } else {
        // skip half: direct guarded float4 stores
        if (r < N_NODES) {
            #pragma unroll
            for (int nf = 0; nf < 8; ++nf) {
                f32x4 v = acc[nf];
                *(float4*)(out + (size_t)r * DOUT + nf * 16 + lq * 4) =
                    make_float4(v[0], v[1], v[2], v[3]);
            }
        }
    }
}

// ---- K2b: per-bucket CSR build: deg/ofs (bucket-based) + srcs scatter ----
__global__ __launch_bounds__(256) void k_csr(const int* __restrict__ bucketCnt,
                                             const unsigned* __restrict__ payload,
                                             int* __restrict__ deg,
                                             int* __restrict__ ofs,
                                             int* __restrict__ srcs) {
    __shared__ int h[256];
    __shared__ int cur[256];
    __shared__ int sc[256];
    const int b = blockIdx.x;
    const int t = threadIdx.x;
    int cnt = bucketCnt[b];
    if (cnt > CAP) cnt = CAP;
    const unsigned* __restrict__ pl = payload + ((size_t)b << 13);

    h[t] = 0;
    __syncthreads();
    for (int i = t; i < cnt; i += 256) atomicAdd(&h[pl[i] >> 16], 1);
    __syncthreads();
    int v = h[t];
    sc[t] = v;
    __syncthreads();
    #pragma unroll
    for (int off = 1; off < 256; off <<= 1) {
        int u = (t >= off) ? sc[t - off] : 0;
        __syncthreads();
        sc[t] += u;
        __syncthreads();
    }
    int ex = sc[t] - v;              // exclusive local prefix
    cur[t] = ex;
    int n = (b << 8) + t;
    if (n < N_NODES) { deg[n] = v; ofs[n] = (b << 13) + ex; }
    __syncthreads();
    for (int i = t; i < cnt; i += 256) {
        unsigned p = pl[i];
        int pos = atomicAdd(&cur[p >> 16], 1);
        srcs[((size_t)b << 13) + pos] = (int)(p & 0xFFFFu);
    }
}

// ---- K3: per-node gather (R12 structure, pinned at its gather floor ~47us) ----
__global__ __launch_bounds__(128) void k_gat(const int* __restrict__ ofs,
                                             const int* __restrict__ deg,
                                             const int* __restrict__ srcs,
                                             const float* __restrict__ as_,
                                             const float* __restrict__ ad_,
                                             const unsigned short* __restrict__ hb,
                                             float* __restrict__ out) {
    __shared__ float EL[2][NHEAD * ELP];   // 2 x 4.2 KB
    __shared__ int   SRC[2][DMAX];         // 2 x 1 KB

    const int sub = threadIdx.x >> 6;      // node slot in block
    const int k   = threadIdx.x & 63;
    const int hd  = k >> 4;
    const int l16 = k & 15;
    const int n = blockIdx.x * 2 + sub;    // 25000*2 == 50000 exactly
    const int o = ofs[n];
    const int d = deg[n];
    const unsigned* __restrict__ hbu = (const unsigned*)hb;
    float* ELn = EL[sub];
    int*   SRCn = SRC[sub];

    int fast = __syncthreads_and(d <= DMAX);   // block-uniform branch

    if (fast) {
        const float4 adv4 = *(const float4*)(ad_ + (size_t)n * 4);
        for (int e = k; e < d; e += 64) {
            int s = srcs[o + e];
            SRCn[e] = s;
            float4 a4 = *(const float4*)(as_ + (size_t)s * 4);
            float e0 = a4.x + adv4.x, e1 = a4.y + adv4.y;
            float e2 = a4.z + adv4.z, e3 = a4.w + adv4.w;
            ELn[0 * ELP + e] = (e0 > 0.0f) ? e0 : NEG_SLOPE * e0;
            ELn[1 * ELP + e] = (e1 > 0.0f) ? e1 : NEG_SLOPE * e1;
            ELn[2 * ELP + e] = (e2 > 0.0f) ? e2 : NEG_SLOPE * e2;
            ELn[3 * ELP + e] = (e3 > 0.0f) ? e3 : NEG_SLOPE * e3;
        }
        __syncthreads();
        float m = -3.4e38f;
        for (int i = l16; i < d; i += 16) m = fmaxf(m, ELn[hd * ELP + i]);
        #pragma unroll
        for (int off = 8; off; off >>= 1) m = fmaxf(m, __shfl_xor(m, off));
        float den = 0.0f;
        for (int i = l16; i < d; i += 16) {
            float p = __expf(ELn[hd * ELP + i] - m);
            ELn[hd * ELP + i] = p;
            den += p;
        }
        #pragma unroll
        for (int off = 8; off; off >>= 1) den += __shfl_xor(den, off);
        __syncthreads();
        float num0 = 0.0f, num1 = 0.0f;
        int i = 0;
        for (; i + 4 <= d; i += 4) {
            int s0 = SRCn[i], s1 = SRCn[i + 1], s2 = SRCn[i + 2], s3 = SRCn[i + 3];
            unsigned u0 = hbu[(size_t)s0 * (DOUT / 2) + k];
            unsigned u1 = hbu[(size_t)s1 * (DOUT / 2) + k];
            unsigned u2 = hbu[(size_t)s2 * (DOUT / 2) + k];
            unsigned u3 = hbu[(size_t)s3 * (DOUT / 2) + k];
            float p0 = ELn[hd * ELP + i];
            float p1 = ELn[hd * ELP + i + 1];
            float p2 = ELn[hd * ELP + i + 2];
            float p3 = ELn[hd * ELP + i + 3];
            num0 = fmaf(p0, bf2f((unsigned short)(u0 & 0xffff)), num0);
            num1 = fmaf(p0, bf2f((unsigned short)(u0 >> 16)), num1);
            num0 = fmaf(p1, bf2f((unsigned short)(u1 & 0xffff)), num0);
            num1 = fmaf(p1, bf2f((unsigned short)(u1 >> 16)), num1);
            num0 = fmaf(p2, bf2f((unsigned short)(u2 & 0xffff)), num0);
            num1 = fmaf(p2, bf2f((unsigned short)(u2 >> 16)), num1);
            num0 = fmaf(p3, bf2f((unsigned short)(u3 & 0xffff)), num0);
            num1 = fmaf(p3, bf2f((unsigned short)(u3 >> 16)), num1);
        }
        for (; i < d; ++i) {
            float p = ELn[hd * ELP + i];
            int s = SRCn[i];
            unsigned u = hbu[(size_t)s * (DOUT / 2) + k];
            num0 = fmaf(p, bf2f((unsigned short)(u & 0xffff)), num0);
            num1 = fmaf(p, bf2f((unsigned short)(u >> 16)), num1);
        }
        float inv = 1.0f / (den + EPS_F);
        float2* op = (float2*)(out + (size_t)n * DOUT + 2 * k);
        float2 sk = *op;
        *op = make_float2(num0 * inv + sk.x, num1 * inv + sk.y);
    } else {
        const float adv = ad_[(size_t)n * 4 + hd];
        float m = -3.4e38f;
        for (int i = 0; i < d; ++i) {
            float el = as_[(size_t)srcs[o + i] * 4 + hd] + adv;
            el = (el > 0.0f) ? el : NEG_SLOPE * el;
            m = fmaxf(m, el);
        }
        float den = 0.0f, num0 = 0.0f, num1 = 0.0f;
        for (int i = 0; i < d; ++i) {
            int s = srcs[o + i];
            float el = as_[(size_t)s * 4 + hd] + adv;
            el = (el > 0.0f) ? el : NEG_SLOPE * el;
            float p = __expf(el - m);
            den += p;
            unsigned u = hbu[(size_t)s * (DOUT / 2) + k];
            num0 = fmaf(p, bf2f((unsigned short)(u & 0xffff)), num0);
            num1 = fmaf(p, bf2f((unsigned short)(u >> 16)), num1);
        }
        float inv = 1.0f / (den + EPS_F);
        float2* op = (float2*)(out + (size_t)n * DOUT + 2 * k);
        float2 sk = *op;
        *op = make_float2(num0 * inv + sk.x, num1 * inv + sk.y);
    }
}

extern "C" void kernel_launch(void* const* d_in, const int* in_sizes, int n_in,
                              void* d_out, int out_size, void* d_ws, size_t ws_size,
                              hipStream_t stream) {
    const float* x   = (const float*)d_in[0];
    const float* Wp  = (const float*)d_in[1];
    const float* att = (const float*)d_in[2];
    const float* Ws  = (const float*)d_in[3];
    const int*   ei  = (const int*)d_in[4];
    float* out = (float*)d_out;

    char* ws = (char*)d_ws;
    unsigned short* hb        = (unsigned short*)(ws);              // 12,812,288 B (50048 rows)
    unsigned short* Wt        = (unsigned short*)(ws + 12812288);   // 65,536 B
    float*          as_       = (float*)(ws + 12877824);            // 800,768 B
    float*          ad_       = (float*)(ws + 13678592);            // 800,768 B
    int*            deg       = (int*)(ws + 14479360);              // 200,704 B
    int*            ofs       = (int*)(ws + 14680064);              // 200,704 B
    unsigned*       payload   = (unsigned*)(ws + 14880768);         // 6,422,528 B
    int*            srcs      = (int*)(ws + 21303296);              // 6,422,528 B
    int*            bucketCnt = (int*)(ws + 27725824);              // 1,024 B
    int*            flag      = (int*)(ws + 27726848);

    k_prep<<<257, 128, 0, stream>>>(Wp, Ws, ei, Wt, bucketCnt, flag);
    k_gemm_part<<<256 + 2 * NGB, 256, 0, stream>>>(
        x, Wt, att, ei, flag, bucketCnt, payload, hb, as_, ad_, out);
    k_csr<<<NB, 256, 0, stream>>>(bucketCnt, payload, deg, ofs, srcs);
    k_gat<<<N_NODES / 2, 128, 0, stream>>>(ofs, deg, srcs, as_, ad_, hb, out);
}